// Round 6
// baseline (793.781 us; speedup 1.0000x reference)
//
#include <hip/hip_runtime.h>

#define TTOK 4096
#define DDIM 1024
#define HDIM 4096
#define NEXP 64
#define CAP  512
#define NASN (TTOK*3)

typedef unsigned short u16;
typedef __attribute__((ext_vector_type(8))) short s16x8;
typedef __attribute__((ext_vector_type(4))) short s16x4;
typedef __attribute__((ext_vector_type(4))) float f32x4;

__device__ __forceinline__ u16 f2bf(float f) {
  union { float f; unsigned u; } v; v.f = f;
  unsigned u = v.u;
  return (u16)((u + 0x7fffu + ((u >> 16) & 1u)) >> 16);
}

__device__ __forceinline__ void gl_lds16(const void* g, void* l) {
  __builtin_amdgcn_global_load_lds(
      (const __attribute__((address_space(1))) void*)g,
      (__attribute__((address_space(3))) void*)l, 16, 0, 0);
}

// ---------------- fast zero for the output (atomicAdd target) ----------------
__global__ __launch_bounds__(256) void zero_out(float4* __restrict__ p, int n4) {
  int i = blockIdx.x * 256 + threadIdx.x;
  int st = gridDim.x * 256;
  for (; i < n4; i += st) p[i] = (float4){0.f, 0.f, 0.f, 0.f};
}

// ---------------- gating: logits + top-3 + softmax ----------------
__global__ __launch_bounds__(512) void gate_topk(
    const float* __restrict__ x, const float* __restrict__ gw,
    const float* __restrict__ gb, int* __restrict__ fe, float* __restrict__ fg)
{
  int lane = threadIdx.x & 63;
  int wid  = threadIdx.x >> 6;
  int t = blockIdx.x * 8 + wid;
  const float* xr = x + (size_t)t * DDIM;
  float acc = gb[lane];
  #pragma unroll 4
  for (int d = 0; d < DDIM; d++) acc += xr[d] * gw[d * NEXP + lane];

  float v = acc;
  float bv[3]; int bi[3];
  #pragma unroll
  for (int j = 0; j < 3; j++) {
    float mv = v; int mi = lane;
    #pragma unroll
    for (int off = 32; off; off >>= 1) {
      float ov = __shfl_xor(mv, off);
      int   oi = __shfl_xor(mi, off);
      if (ov > mv || (ov == mv && oi < mi)) { mv = ov; mi = oi; }
    }
    bv[j] = mv; bi[j] = mi;
    if (lane == mi) v = -3.4e38f;
  }
  if (lane == 0) {
    float e1 = expf(bv[1] - bv[0]), e2 = expf(bv[2] - bv[0]);
    float inv = 1.0f / (1.0f + e1 + e2);
    fe[t*3+0] = bi[0]; fe[t*3+1] = bi[1]; fe[t*3+2] = bi[2];
    fg[t*3+0] = inv;   fg[t*3+1] = e1*inv; fg[t*3+2] = e2*inv;
  }
}

// ------- order-preserving per-expert slot assignment (exact ref semantics) -------
__global__ __launch_bounds__(64) void scan_pos(
    const int* __restrict__ fe, int* __restrict__ posA,
    int* __restrict__ s2a, int* __restrict__ cnt)
{
  int e = blockIdx.x, lane = threadIdx.x;
  int base = 0;
  for (int i0 = 0; i0 < NASN; i0 += 64) {
    int i = i0 + lane;
    bool m = (fe[i] == e);
    unsigned long long bal = __ballot(m);
    int below = __popcll(bal & ((1ull << lane) - 1ull));
    if (m) {
      int p = base + below;
      posA[i] = p;
      if (p < CAP) s2a[e * CAP + p] = i;
    }
    base += __popcll(bal);
  }
  if (lane == 0) cnt[e] = base < CAP ? base : CAP;
}

// ---------------- dispatch: scatter x rows into bf16 expert buffers ----------------
__global__ __launch_bounds__(64) void dispatch(
    const float* __restrict__ x, const int* __restrict__ fe,
    const int* __restrict__ posA, u16* __restrict__ bufA)
{
  int a = blockIdx.x;
  int p = posA[a];
  if (p >= CAP) return;
  int e = fe[a];
  int tok = a / 3;
  int l = threadIdx.x;
  const float4* xr = (const float4*)(x + (size_t)tok * DDIM);
  u16* dst = bufA + ((size_t)e * CAP + p) * DDIM;
  #pragma unroll
  for (int j = 0; j < 4; j++) {
    float4 v = xr[j * 64 + l];
    uint2 u;
    u.x = (unsigned)f2bf(v.x) | ((unsigned)f2bf(v.y) << 16);
    u.y = (unsigned)f2bf(v.z) | ((unsigned)f2bf(v.w) << 16);
    *(uint2*)(dst + (size_t)(j * 64 + l) * 4) = u;
  }
}

// ---------------- expert GEMM: BM=256, BN=128, BK=64, 8 waves (512 thr) ----------------
// 4 waves/SIMD target (launch_bounds(512,4), LDS 50KB -> 2 blocks/CU) for HBM
// stream/compute overlap. Counted-vmcnt pipeline: B(t+1)'s 16 loads stay in
// flight through the MFMA phase. SK: split-K factor (EPI==2 only; ks>0 skips bias).
template<int KTOT, int NTOT, int EPI, int SK>
__global__ __launch_bounds__(512, 4) void moe_gemm(
    const u16* __restrict__ Abuf, const float* __restrict__ W,
    const float* __restrict__ bias, u16* __restrict__ hout,
    float* __restrict__ out, const int* __restrict__ cnt,
    const int* __restrict__ s2a, const float* __restrict__ fg, int g0)
{
  constexpr int NCT = NTOT / 128;
  constexpr int NT  = KTOT / 64 / SK;
  int NB = gridDim.x;
  int b = blockIdx.x;
  int L = (b & 7) * (NB >> 3) + (b >> 3);   // XCD-bijective swizzle (NB % 8 == 0)
  int tcol = L % NCT;
  int rt   = (L / NCT) & 1;
  int rest = L / (NCT * 2);
  int ks   = rest % SK;
  int el   = rest / SK;
  int e    = g0 + el;
  int cnte = cnt[e];
  int c0   = rt * 256;
  if (c0 >= cnte) return;
  int n0 = tcol * 128;
  int koff = ks * (KTOT / SK);

  int tid = threadIdx.x, l = tid & 63, w = tid >> 6;

  __shared__ char AsB[256 * 128];   // [256 rows][64 bf16] chunk-swizzled
  __shared__ char BsB[128 * 136];   // [128 n][64+4 bf16] K-major transposed

  const u16* Arows = Abuf + ((size_t)((EPI == 1 ? e : el)) * CAP + c0) * (size_t)KTOT + koff;
  const float* We = W + (size_t)e * KTOT * NTOT;

  // per-thread B staging geometry: n = tid&127, k-group = tid>>7 (16 k each)
  int bn = tid & 127, bkg = tid >> 7;
  const float* Wt = We + (size_t)(koff + bkg * 16) * NTOT + n0 + bn;
  char* BsW = BsB + bn * 136 + bkg * 32;

  float brB[16];
  #define LOADB(t) { \
    const float* p_ = Wt + (size_t)(t) * 64 * NTOT; \
    _Pragma("unroll") \
    for (int j_ = 0; j_ < 16; j_++) \
      brB[j_] = p_[(size_t)j_ * NTOT]; \
    }
  #define STOREB() { \
    _Pragma("unroll") \
    for (int j_ = 0; j_ < 4; j_++) { \
      uint2 u_; \
      u_.x = (unsigned)f2bf(brB[j_*4+0]) | ((unsigned)f2bf(brB[j_*4+1]) << 16); \
      u_.y = (unsigned)f2bf(brB[j_*4+2]) | ((unsigned)f2bf(brB[j_*4+3]) << 16); \
      *(uint2*)(BsW + j_ * 8) = u_; \
    } }

  f32x4 acc[2][8];
  #pragma unroll
  for (int m = 0; m < 2; m++)
    #pragma unroll
    for (int nn = 0; nn < 8; nn++)
      acc[m][nn] = (f32x4){0.f, 0.f, 0.f, 0.f};

  LOADB(0);   // prologue prefetch

  for (int t = 0; t < NT; ++t) {
    // --- stage A(t): 4 gl_lds per wave (1KB each), source chunk-swizzled ---
    #pragma unroll
    for (int i = 0; i < 4; i++) {
      int r = i * 64 + w * 8 + (l >> 3);
      int cswz = (l & 7) ^ (r & 7);
      const char* gsrc = (const char*)(Arows + (size_t)r * KTOT + (size_t)t * 64) + cswz * 16;
      gl_lds16(gsrc, AsB + (i * 64 + w * 8) * 128);
    }
    // --- convert+store B(t): auto-wait drains B(t) regs only (A gl_lds younger) ---
    STOREB();
    __builtin_amdgcn_sched_barrier(0);
    // --- prefetch B(t+1): issue 16 loads, leave in flight across the barrier ---
    if (t + 1 < NT) {
      LOADB(t + 1);
      __builtin_amdgcn_sched_barrier(0);
      asm volatile("s_waitcnt vmcnt(16)" ::: "memory");   // A(t) done; B(t+1) in flight
    } else {
      asm volatile("s_waitcnt vmcnt(0)" ::: "memory");    // last iter: drain A(t)
    }
    asm volatile("s_waitcnt lgkmcnt(0)" ::: "memory");    // ds_writes visible
    __builtin_amdgcn_sched_barrier(0);
    __builtin_amdgcn_s_barrier();
    __builtin_amdgcn_sched_barrier(0);

    // --- MFMA phase: wave w owns rows [w*32, w*32+32) ---
    #pragma unroll
    for (int k2 = 0; k2 < 2; k2++) {
      int kb = k2 * 32;
      s16x8 af[2];
      #pragma unroll
      for (int m = 0; m < 2; m++) {
        int R = w * 32 + m * 16 + (l & 15);
        int chunk = (kb >> 3) + (l >> 4);
        int sc = chunk ^ (R & 7);
        af[m] = *(const s16x8*)(AsB + R * 128 + sc * 16);
      }
      #pragma unroll
      for (int nn = 0; nn < 8; nn++) {
        int Nn = nn * 16 + (l & 15);
        int kk = kb + (l >> 4) * 8;
        const char* bp = BsB + Nn * 136 + kk * 2;
        union { s16x8 v8; s16x4 v4[2]; } bu;
        bu.v4[0] = *(const s16x4*)bp;
        bu.v4[1] = *(const s16x4*)(bp + 8);
        #pragma unroll
        for (int m = 0; m < 2; m++)
          acc[m][nn] = __builtin_amdgcn_mfma_f32_16x16x32_bf16(af[m], bu.v8, acc[m][nn], 0, 0, 0);
      }
    }
    __builtin_amdgcn_s_barrier();
    __builtin_amdgcn_sched_barrier(0);
  }

  int lr = l >> 4, lc = l & 15;
  float bv[8];
  #pragma unroll
  for (int nn = 0; nn < 8; nn++)
    bv[nn] = (SK > 1 && ks != 0) ? 0.f : bias[(size_t)e * NTOT + n0 + nn * 16 + lc];

  if (EPI == 1) {
    #pragma unroll
    for (int m = 0; m < 2; m++)
      #pragma unroll
      for (int q = 0; q < 4; q++) {
        int rowL = w * 32 + m * 16 + lr * 4 + q;
        if (c0 + rowL < cnte) {     // clip: rows >= cnte never read usefully
          #pragma unroll
          for (int nn = 0; nn < 8; nn++) {
            float vv = acc[m][nn][q] + bv[nn];
            vv = 0.5f * vv * (1.0f + erff(vv * 0.70710678118f));
            hout[(size_t)(el * CAP + c0 + rowL) * NTOT + (n0 + nn * 16 + lc)] = f2bf(vv);
          }
        }
      }
  } else {
    #pragma unroll
    for (int m = 0; m < 2; m++) {
      int rowbase = w * 32 + m * 16 + lr * 4;
      #pragma unroll
      for (int q = 0; q < 4; q++) {
        int slot = c0 + rowbase + q;
        if (slot < cnte) {
          int aidx = s2a[e * CAP + slot];
          int tok = aidx / 3;
          float gg = fg[aidx];
          #pragma unroll
          for (int nn = 0; nn < 8; nn++) {
            float vv = (acc[m][nn][q] + bv[nn]) * gg;
            atomicAdd(out + (size_t)tok * DDIM + (n0 + nn * 16 + lc), vv);
          }
        }
      }
    }
  }
}

extern "C" void kernel_launch(void* const* d_in, const int* in_sizes, int n_in,
                              void* d_out, int out_size, void* d_ws, size_t ws_size,
                              hipStream_t stream) {
  (void)in_sizes; (void)n_in; (void)ws_size;
  const float* x  = (const float*)d_in[0];
  const float* gw = (const float*)d_in[1];
  const float* gb = (const float*)d_in[2];
  const float* w1 = (const float*)d_in[3];
  const float* b1 = (const float*)d_in[4];
  const float* w2 = (const float*)d_in[5];
  const float* b2 = (const float*)d_in[6];
  float* out = (float*)d_out;

  char* ws = (char*)d_ws;
  int*   fe   = (int*)(ws);
  float* fg   = (float*)(ws + 49152);
  int*   posA = (int*)(ws + 98304);
  int*   s2a  = (int*)(ws + 147456);
  int*   cnt  = (int*)(ws + 278528);
  u16*   bufA = (u16*)(ws + (1 << 20));
  u16*   hbuf = (u16*)(ws + (1 << 20) + 67108864ull);

  zero_out<<<1024, 256, 0, stream>>>((float4*)out, out_size / 4);
  gate_topk<<<TTOK / 8, 512, 0, stream>>>(x, gw, gb, fe, fg);
  scan_pos<<<NEXP, 64, 0, stream>>>(fe, posA, s2a, cnt);
  dispatch<<<NASN, 64, 0, stream>>>(x, fe, posA, bufA);

  moe_gemm<DDIM, HDIM, 1, 1><<<NEXP * 2 * (HDIM / 128), 512, 0, stream>>>(
      bufA, w1, b1, hbuf, nullptr, cnt, nullptr, nullptr, 0);
  moe_gemm<HDIM, DDIM, 2, 2><<<NEXP * 2 * (DDIM / 128) * 2, 512, 0, stream>>>(
      hbuf, w2, b2, nullptr, out, cnt, s2a, fg, 0);
}

// Round 8
// 694.436 us; speedup vs baseline: 1.1431x; 1.1431x over previous
//
#include <hip/hip_runtime.h>

#define TTOK 4096
#define DDIM 1024
#define HDIM 4096
#define NEXP 64
#define CAP  512
#define NASN (TTOK*3)

typedef unsigned short u16;
typedef __attribute__((ext_vector_type(8))) short s16x8;
typedef __attribute__((ext_vector_type(4))) short s16x4;
typedef __attribute__((ext_vector_type(4))) float f32x4;

__device__ __forceinline__ u16 f2bf(float f) {
  union { float f; unsigned u; } v; v.f = f;
  unsigned u = v.u;
  return (u16)((u + 0x7fffu + ((u >> 16) & 1u)) >> 16);
}

__device__ __forceinline__ void gl_lds16(const void* g, void* l) {
  __builtin_amdgcn_global_load_lds(
      (const __attribute__((address_space(1))) void*)g,
      (__attribute__((address_space(3))) void*)l, 16, 0, 0);
}

// ---------------- fast zero for the output (atomicAdd target) ----------------
__global__ __launch_bounds__(256) void zero_out(float4* __restrict__ p, int n4) {
  int i = blockIdx.x * 256 + threadIdx.x;
  int st = gridDim.x * 256;
  for (; i < n4; i += st) p[i] = (float4){0.f, 0.f, 0.f, 0.f};
}

// ---------------- gating: logits + top-3 + softmax ----------------
__global__ __launch_bounds__(512) void gate_topk(
    const float* __restrict__ x, const float* __restrict__ gw,
    const float* __restrict__ gb, int* __restrict__ fe, float* __restrict__ fg)
{
  int lane = threadIdx.x & 63;
  int wid  = threadIdx.x >> 6;
  int t = blockIdx.x * 8 + wid;
  const float* xr = x + (size_t)t * DDIM;
  float acc = gb[lane];
  #pragma unroll 4
  for (int d = 0; d < DDIM; d++) acc += xr[d] * gw[d * NEXP + lane];

  float v = acc;
  float bv[3]; int bi[3];
  #pragma unroll
  for (int j = 0; j < 3; j++) {
    float mv = v; int mi = lane;
    #pragma unroll
    for (int off = 32; off; off >>= 1) {
      float ov = __shfl_xor(mv, off);
      int   oi = __shfl_xor(mi, off);
      if (ov > mv || (ov == mv && oi < mi)) { mv = ov; mi = oi; }
    }
    bv[j] = mv; bi[j] = mi;
    if (lane == mi) v = -3.4e38f;
  }
  if (lane == 0) {
    float e1 = expf(bv[1] - bv[0]), e2 = expf(bv[2] - bv[0]);
    float inv = 1.0f / (1.0f + e1 + e2);
    fe[t*3+0] = bi[0]; fe[t*3+1] = bi[1]; fe[t*3+2] = bi[2];
    fg[t*3+0] = inv;   fg[t*3+1] = e1*inv; fg[t*3+2] = e2*inv;
  }
}

// ------- order-preserving per-expert slot assignment (exact ref semantics) -------
__global__ __launch_bounds__(64) void scan_pos(
    const int* __restrict__ fe, int* __restrict__ posA,
    int* __restrict__ s2a, int* __restrict__ cnt)
{
  int e = blockIdx.x, lane = threadIdx.x;
  int base = 0;
  for (int i0 = 0; i0 < NASN; i0 += 64) {
    int i = i0 + lane;
    bool m = (fe[i] == e);
    unsigned long long bal = __ballot(m);
    int below = __popcll(bal & ((1ull << lane) - 1ull));
    if (m) {
      int p = base + below;
      posA[i] = p;
      if (p < CAP) s2a[e * CAP + p] = i;
    }
    base += __popcll(bal);
  }
  if (lane == 0) cnt[e] = base < CAP ? base : CAP;
}

// ---------------- dispatch: scatter x rows into bf16 expert buffers ----------------
__global__ __launch_bounds__(64) void dispatch(
    const float* __restrict__ x, const int* __restrict__ fe,
    const int* __restrict__ posA, u16* __restrict__ bufA)
{
  int a = blockIdx.x;
  int p = posA[a];
  if (p >= CAP) return;
  int e = fe[a];
  int tok = a / 3;
  int l = threadIdx.x;
  const float4* xr = (const float4*)(x + (size_t)tok * DDIM);
  u16* dst = bufA + ((size_t)e * CAP + p) * DDIM;
  #pragma unroll
  for (int j = 0; j < 4; j++) {
    float4 v = xr[j * 64 + l];
    uint2 u;
    u.x = (unsigned)f2bf(v.x) | ((unsigned)f2bf(v.y) << 16);
    u.y = (unsigned)f2bf(v.z) | ((unsigned)f2bf(v.w) << 16);
    *(uint2*)(dst + (size_t)(j * 64 + l) * 4) = u;
  }
}

// ---------------- expert GEMM: BM=256, BN=128, BK=64, 4 waves ----------------
// Counted-vmcnt pipeline (T4): B(t+1)'s 8 float4 loads stay in flight through
// the MFMA phase. B staging is float4 (1KB per wave-request): thread owns
// (kb = (tid>>5)*8 rows, n4 = tid&31 column-group), writes K-major LDS as
// 8x ds_write_b64 (k..k+3 packed per column).
// EPI==1: h = gelu(A*W1 + b1) -> bf16   EPI==2: atomic gated combine of A*W2 + b2
template<int KTOT, int NTOT, int EPI>
__global__ __launch_bounds__(256, 2) void moe_gemm(
    const u16* __restrict__ Abuf, const float* __restrict__ W,
    const float* __restrict__ bias, u16* __restrict__ hout,
    float* __restrict__ out, const int* __restrict__ cnt,
    const int* __restrict__ s2a, const float* __restrict__ fg, int g0)
{
  constexpr int NCT = NTOT / 128;
  constexpr int NT  = KTOT / 64;
  int NB = gridDim.x;
  int b = blockIdx.x;
  int L = (b & 7) * (NB >> 3) + (b >> 3);   // XCD-bijective swizzle (NB % 8 == 0)
  int tcol = L % NCT;
  int rt   = (L / NCT) & 1;
  int el   = L / (NCT * 2);
  int e    = g0 + el;
  int cnte = cnt[e];
  int c0   = rt * 256;
  if (c0 >= cnte) return;
  int n0 = tcol * 128;

  int tid = threadIdx.x, l = tid & 63, w = tid >> 6;

  __shared__ char AsB[256 * 128];   // [256 rows][64 bf16] chunk-swizzled
  __shared__ char BsB[128 * 136];   // [128 n][64+4 bf16] K-major transposed

  const u16* Arows = Abuf + ((size_t)((EPI == 1 ? e : el)) * CAP + c0) * (size_t)KTOT;
  const float* We = W + (size_t)e * KTOT * NTOT;

  // per-thread B staging geometry: n4 = tid&31 (float4 col group), kb = (tid>>5)*8
  int bn4 = tid & 31, bkb = (tid >> 5) * 8;
  const float* Wt = We + (size_t)bkb * NTOT + n0 + bn4 * 4;
  char* BsW = BsB + (bn4 * 4) * 136 + bkb * 2;

  float4 brB4[8];
  #define LOADB(t) { \
    const float* p_ = Wt + (size_t)(t) * 64 * NTOT; \
    _Pragma("unroll") \
    for (int j_ = 0; j_ < 8; j_++) \
      brB4[j_] = *(const float4*)(p_ + (size_t)j_ * NTOT); \
    }
  // pack k..k+3 (jj=0) and k+4..k+7 (jj=4) per column c -> b64 writes
  #define STOREB() { \
    _Pragma("unroll") \
    for (int c_ = 0; c_ < 4; c_++) { \
      float v0_ = (c_==0?brB4[0].x:c_==1?brB4[0].y:c_==2?brB4[0].z:brB4[0].w); \
      float v1_ = (c_==0?brB4[1].x:c_==1?brB4[1].y:c_==2?brB4[1].z:brB4[1].w); \
      float v2_ = (c_==0?brB4[2].x:c_==1?brB4[2].y:c_==2?brB4[2].z:brB4[2].w); \
      float v3_ = (c_==0?brB4[3].x:c_==1?brB4[3].y:c_==2?brB4[3].z:brB4[3].w); \
      float v4_ = (c_==0?brB4[4].x:c_==1?brB4[4].y:c_==2?brB4[4].z:brB4[4].w); \
      float v5_ = (c_==0?brB4[5].x:c_==1?brB4[5].y:c_==2?brB4[5].z:brB4[5].w); \
      float v6_ = (c_==0?brB4[6].x:c_==1?brB4[6].y:c_==2?brB4[6].z:brB4[6].w); \
      float v7_ = (c_==0?brB4[7].x:c_==1?brB4[7].y:c_==2?brB4[7].z:brB4[7].w); \
      uint2 ua_, ub_; \
      ua_.x = (unsigned)f2bf(v0_) | ((unsigned)f2bf(v1_) << 16); \
      ua_.y = (unsigned)f2bf(v2_) | ((unsigned)f2bf(v3_) << 16); \
      ub_.x = (unsigned)f2bf(v4_) | ((unsigned)f2bf(v5_) << 16); \
      ub_.y = (unsigned)f2bf(v6_) | ((unsigned)f2bf(v7_) << 16); \
      *(uint2*)(BsW + c_ * 136) = ua_; \
      *(uint2*)(BsW + c_ * 136 + 8) = ub_; \
    } }

  f32x4 acc[4][8];
  #pragma unroll
  for (int m = 0; m < 4; m++)
    #pragma unroll
    for (int nn = 0; nn < 8; nn++)
      acc[m][nn] = (f32x4){0.f, 0.f, 0.f, 0.f};

  LOADB(0);   // prologue prefetch

  for (int t = 0; t < NT; ++t) {
    // --- stage A(t): 8 gl_lds per wave, source chunk-swizzled ---
    #pragma unroll
    for (int i = 0; i < 8; i++) {
      int r = i * 32 + w * 8 + (l >> 3);
      int cswz = (l & 7) ^ (r & 7);
      const char* gsrc = (const char*)(Arows + (size_t)r * KTOT + (size_t)t * 64) + cswz * 16;
      gl_lds16(gsrc, AsB + (i * 32 + w * 8) * 128);
    }
    // --- convert+store B(t): auto-wait drains B(t) regs only (A gl_lds younger) ---
    STOREB();
    __builtin_amdgcn_sched_barrier(0);
    // --- prefetch B(t+1): issue 8 float4 loads, leave in flight across the barrier ---
    if (t + 1 < NT) {
      LOADB(t + 1);
      __builtin_amdgcn_sched_barrier(0);
      asm volatile("s_waitcnt vmcnt(8)" ::: "memory");    // A(t) done; B(t+1) in flight
    } else {
      asm volatile("s_waitcnt vmcnt(0)" ::: "memory");    // last iter: drain A(t)
    }
    asm volatile("s_waitcnt lgkmcnt(0)" ::: "memory");    // ds_writes visible
    __builtin_amdgcn_sched_barrier(0);
    __builtin_amdgcn_s_barrier();
    __builtin_amdgcn_sched_barrier(0);

    // --- MFMA phase ---
    #pragma unroll
    for (int k2 = 0; k2 < 2; k2++) {
      int kb = k2 * 32;
      s16x8 af[4], bf8[8];
      #pragma unroll
      for (int m = 0; m < 4; m++) {
        int R = w * 64 + m * 16 + (l & 15);
        int chunk = (kb >> 3) + (l >> 4);
        int sc = chunk ^ (R & 7);
        af[m] = *(const s16x8*)(AsB + R * 128 + sc * 16);
      }
      #pragma unroll
      for (int nn = 0; nn < 8; nn++) {
        int Nn = nn * 16 + (l & 15);
        int kk = kb + (l >> 4) * 8;
        const char* bp = BsB + Nn * 136 + kk * 2;
        union { s16x8 v8; s16x4 v4[2]; } bu;
        bu.v4[0] = *(const s16x4*)bp;
        bu.v4[1] = *(const s16x4*)(bp + 8);
        bf8[nn] = bu.v8;
      }
      #pragma unroll
      for (int m = 0; m < 4; m++)
        #pragma unroll
        for (int nn = 0; nn < 8; nn++)
          acc[m][nn] = __builtin_amdgcn_mfma_f32_16x16x32_bf16(af[m], bf8[nn], acc[m][nn], 0, 0, 0);
    }
    __builtin_amdgcn_s_barrier();
    __builtin_amdgcn_sched_barrier(0);
  }

  int lr = l >> 4, lc = l & 15;
  float bv[8];
  #pragma unroll
  for (int nn = 0; nn < 8; nn++) bv[nn] = bias[(size_t)e * NTOT + n0 + nn * 16 + lc];

  if (EPI == 1) {
    #pragma unroll
    for (int m = 0; m < 4; m++)
      #pragma unroll
      for (int q = 0; q < 4; q++) {
        int rowL = w * 64 + m * 16 + lr * 4 + q;
        if (c0 + rowL < cnte) {     // clip: rows >= cnte never read usefully
          #pragma unroll
          for (int nn = 0; nn < 8; nn++) {
            float vv = acc[m][nn][q] + bv[nn];
            vv = 0.5f * vv * (1.0f + erff(vv * 0.70710678118f));
            hout[(size_t)(el * CAP + c0 + rowL) * NTOT + (n0 + nn * 16 + lc)] = f2bf(vv);
          }
        }
      }
  } else {
    #pragma unroll
    for (int m = 0; m < 4; m++) {
      int rowbase = w * 64 + m * 16 + lr * 4;
      #pragma unroll
      for (int q = 0; q < 4; q++) {
        int slot = c0 + rowbase + q;
        if (slot < cnte) {
          int aidx = s2a[e * CAP + slot];
          int tok = aidx / 3;
          float gg = fg[aidx];
          #pragma unroll
          for (int nn = 0; nn < 8; nn++) {
            float vv = (acc[m][nn][q] + bv[nn]) * gg;
            atomicAdd(out + (size_t)tok * DDIM + (n0 + nn * 16 + lc), vv);
          }
        }
      }
    }
  }
}

extern "C" void kernel_launch(void* const* d_in, const int* in_sizes, int n_in,
                              void* d_out, int out_size, void* d_ws, size_t ws_size,
                              hipStream_t stream) {
  (void)in_sizes; (void)n_in; (void)ws_size;
  const float* x  = (const float*)d_in[0];
  const float* gw = (const float*)d_in[1];
  const float* gb = (const float*)d_in[2];
  const float* w1 = (const float*)d_in[3];
  const float* b1 = (const float*)d_in[4];
  const float* w2 = (const float*)d_in[5];
  const float* b2 = (const float*)d_in[6];
  float* out = (float*)d_out;

  char* ws = (char*)d_ws;
  int*   fe   = (int*)(ws);
  float* fg   = (float*)(ws + 49152);
  int*   posA = (int*)(ws + 98304);
  int*   s2a  = (int*)(ws + 147456);
  int*   cnt  = (int*)(ws + 278528);
  u16*   bufA = (u16*)(ws + (1 << 20));
  u16*   hbuf = (u16*)(ws + (1 << 20) + 67108864ull);

  zero_out<<<1024, 256, 0, stream>>>((float4*)out, out_size / 4);
  gate_topk<<<TTOK / 8, 512, 0, stream>>>(x, gw, gb, fe, fg);
  scan_pos<<<NEXP, 64, 0, stream>>>(fe, posA, s2a, cnt);
  dispatch<<<NASN, 64, 0, stream>>>(x, fe, posA, bufA);

  moe_gemm<DDIM, HDIM, 1><<<NEXP * 2 * (HDIM / 128), 256, 0, stream>>>(
      bufA, w1, b1, hbuf, nullptr, cnt, nullptr, nullptr, 0);
  moe_gemm<HDIM, DDIM, 2><<<NEXP * 2 * (DDIM / 128), 256, 0, stream>>>(
      hbuf, w2, b2, nullptr, out, cnt, s2a, fg, 0);
}